// Round 11
// baseline (393.682 us; speedup 1.0000x reference)
//
#include <hip/hip_runtime.h>
#include <math.h>

#define W_ 256
#define H_ 256
#define HW 65536
#define CC 64

typedef _Float16 h16;
typedef _Float16 half8 __attribute__((ext_vector_type(8)));
typedef float f32x4  __attribute__((ext_vector_type(4)));
typedef float f32x16 __attribute__((ext_vector_type(16)));

__device__ __forceinline__ unsigned pk2(float a, float b) {
  union { h16 h[2]; unsigned u; } c;
  c.h[0] = (h16)a; c.h[1] = (h16)b;
  return c.u;
}
__device__ __forceinline__ void plswap(unsigned &a, unsigned &b) {
  asm volatile("v_permlane32_swap_b32 %0, %1" : "+v"(a), "+v"(b));
}

// ---------------- weight prep: (w_iem,w_nem) fp32 OIHW -> Bt[co128][k=tap*64+ci] f16 ----------------
__global__ __launch_bounds__(256) void k_wprep(
    const float* __restrict__ wi, const float* __restrict__ wn, h16* __restrict__ Bt)
{
  int i = blockIdx.x * 256 + threadIdx.x;
  if (i >= 128 * 576) return;
  int co = i / 576, k = i - co * 576;
  int tap = k >> 6, ci = k & 63;
  const float* src = (co < 64) ? wi : wn;
  int c = co & 63;
  Bt[i] = (h16)src[(c * 64 + ci) * 9 + tap];
}

// ---------------- weight prep 2: wq,wk,wv,wproj -> f16 [4][64][64]; dw weights -> f16 [2][9][64] ----------------
__global__ __launch_bounds__(256) void k_wprep2(
    const float* __restrict__ wq, const float* __restrict__ wk,
    const float* __restrict__ wv, const float* __restrict__ wp,
    const float* __restrict__ wdw1, const float* __restrict__ wdw2,
    h16* __restrict__ W)
{
  int i = blockIdx.x * 256 + threadIdx.x;   // < 17536
  if (i >= 17536) return;
  if (i < 16384) {
    int m = i >> 12, e = i & 4095;
    const float* s = (m == 0) ? wq : (m == 1) ? wk : (m == 2) ? wv : wp;
    W[i] = (h16)s[e];
  } else {
    int e = i - 16384;                       // < 1152
    int pass = e / 576, rem = e - pass * 576;
    int tap = rem >> 6, c = rem & 63;
    const float* s = pass ? wdw2 : wdw1;
    W[i] = (h16)s[c * 9 + tap];
  }
}

// ---------------- x NCHW fp32 -> xT NHWC f16 (streaming transpose) ----------------
// grid (4, 256, 4): xtile(64px) x y x b; 256 thr.
__global__ __launch_bounds__(256) void k_xpose(
    const float* __restrict__ x, h16* __restrict__ xT)
{
  __shared__ __align__(16) char sm[64 * 132];  // [px64][ch66] f16
  const int tid = threadIdx.x;
  const int xt = blockIdx.x, y = blockIdx.y, b = blockIdx.z;
  const int x0 = xt * 64;
  const float* xb = x + ((size_t)b * CC) * HW + y * W_ + x0;
  const int ci = tid >> 2, q = tid & 3;
#pragma unroll
  for (int k = 0; k < 4; ++k) {
    const int pc = q + k * 4;                // px-chunk (4 px each), 0..15
    float4 v = *(const float4*)(xb + (size_t)ci * HW + pc * 4);
    const int px = pc * 4;
    *(h16*)(sm + (px + 0) * 132 + ci * 2) = (h16)v.x;
    *(h16*)(sm + (px + 1) * 132 + ci * 2) = (h16)v.y;
    *(h16*)(sm + (px + 2) * 132 + ci * 2) = (h16)v.z;
    *(h16*)(sm + (px + 3) * 132 + ci * 2) = (h16)v.w;
  }
  __syncthreads();
  h16* dst = xT + (((size_t)b * 256 + y) * 256 + x0) * 64;
#pragma unroll
  for (int it = 0; it < 2; ++it) {
    int task = tid + it * 256;
    int px = task >> 3, c8 = task & 7;
    int4 d = *(const int4*)(sm + px * 132 + c8 * 16);
    *(int4*)(dst + px * 64 + c8 * 8) = d;
  }
}

// ---------------- fused dual conv3x3 + sigmoid (MFMA f16), input xT NHWC f16 ----------------
// grid (4, 128, 4). block 512 = 8 waves (4 co-waves x 2 px-waves).
__global__ __launch_bounds__(512) void k_conv3x3x2(
    const h16* __restrict__ xT, const h16* __restrict__ Bt,
    h16* __restrict__ T1, h16* __restrict__ T2)
{
  __shared__ __align__(16) char lds[38016];

  const int tid = threadIdx.x;
  const int b = blockIdx.z, ry = blockIdx.y, cx = blockIdx.x;
  const int y0 = ry * 2, x0 = cx * 64;

  // ---- stage xT tile: rows y0-1..y0+2, cols x0-1..x0+64, 64 ch; LDS [pxr 264][ch64] s144 ----
  {
    const h16* xb = xT + ((size_t)b * 256) * 256 * 64;
    int4 zero4; zero4.x = zero4.y = zero4.z = zero4.w = 0;
#pragma unroll
    for (int it = 0; it < 5; ++it) {
      int idx = tid + it * 512;
      if (idx < 2112) {                       // 264 px-rows x 8 chunks
        int pxr = idx >> 3, c8 = idx & 7;
        int r = pxr / 66, c = pxr - r * 66;
        int gy = y0 - 1 + r, gx = x0 - 1 + c;
        int4 d = zero4;
        if ((unsigned)gy < 256u && (unsigned)gx < 256u)
          d = *(const int4*)(xb + ((size_t)(gy * 256 + gx)) * 64 + c8 * 8);
        *(int4*)(lds + pxr * 144 + c8 * 16) = d;
      }
    }
  }
  __syncthreads();

  const int wv = tid >> 6, lane = tid & 63;
  const int wn_ = wv & 3;
  const int wm_ = wv >> 2;
  const int cob = wn_ * 32;
  const int pxb = wm_ * 64;
  const int lg = lane >> 4, lr = lane & 15;

  const char* pB[4];
#pragma unroll
  for (int pi = 0; pi < 4; ++pi) {
    int opx = (pxb + pi * 16 + lr) & 63;
    pB[pi] = lds + (wm_ * 66 + opx) * 144 + lg * 16;
  }
  const h16* wb0 = Bt + (size_t)(cob + lr) * 576 + lg * 8;
  const h16* wb1 = wb0 + 16 * 576;

  f32x4 acc[2][4];
#pragma unroll
  for (int i = 0; i < 2; ++i)
#pragma unroll
    for (int j = 0; j < 4; ++j) acc[i][j] = (f32x4){0.f, 0.f, 0.f, 0.f};

#pragma unroll
  for (int tap = 0; tap < 9; ++tap) {
    const int dy = tap / 3, dx = tap - dy * 3;
#pragma unroll
    for (int kh = 0; kh < 2; ++kh) {
      const int loff = (dy * 66 + dx) * 144 + kh * 64;
      const int koff = tap * 64 + kh * 32;
      half8 a0 = *(const half8*)(wb0 + koff);
      half8 a1 = *(const half8*)(wb1 + koff);
      half8 b0 = *(const half8*)(pB[0] + loff);
      half8 b1 = *(const half8*)(pB[1] + loff);
      half8 b2 = *(const half8*)(pB[2] + loff);
      half8 b3 = *(const half8*)(pB[3] + loff);
      acc[0][0] = __builtin_amdgcn_mfma_f32_16x16x32_f16(a0, b0, acc[0][0], 0, 0, 0);
      acc[0][1] = __builtin_amdgcn_mfma_f32_16x16x32_f16(a0, b1, acc[0][1], 0, 0, 0);
      acc[0][2] = __builtin_amdgcn_mfma_f32_16x16x32_f16(a0, b2, acc[0][2], 0, 0, 0);
      acc[0][3] = __builtin_amdgcn_mfma_f32_16x16x32_f16(a0, b3, acc[0][3], 0, 0, 0);
      acc[1][0] = __builtin_amdgcn_mfma_f32_16x16x32_f16(a1, b0, acc[1][0], 0, 0, 0);
      acc[1][1] = __builtin_amdgcn_mfma_f32_16x16x32_f16(a1, b1, acc[1][1], 0, 0, 0);
      acc[1][2] = __builtin_amdgcn_mfma_f32_16x16x32_f16(a1, b2, acc[1][2], 0, 0, 0);
      acc[1][3] = __builtin_amdgcn_mfma_f32_16x16x32_f16(a1, b3, acc[1][3], 0, 0, 0);
    }
  }
  __syncthreads();   // input tile dead; reuse LDS for output transpose

  // write sigmoid(acc) to LDS O[px 128][co 128] f16, stride 272B
#pragma unroll
  for (int ni = 0; ni < 2; ++ni) {
#pragma unroll
    for (int pi = 0; pi < 4; ++pi) {
      const int opx = (pxb + pi * 16 + lr) & 63;
      const int pxid = wm_ * 64 + opx;
      const int co = cob + ni * 16 + lg * 4;
      float s0 = 1.f / (1.f + __expf(-acc[ni][pi][0]));
      float s1 = 1.f / (1.f + __expf(-acc[ni][pi][1]));
      float s2 = 1.f / (1.f + __expf(-acc[ni][pi][2]));
      float s3 = 1.f / (1.f + __expf(-acc[ni][pi][3]));
      uint2 d; d.x = pk2(s0, s1); d.y = pk2(s2, s3);
      *(uint2*)(lds + pxid * 272 + co * 2) = d;
    }
  }
  __syncthreads();

  {
    int px = tid >> 3, chg = tid & 7;
#pragma unroll
    for (int seg = 0; seg < 4; ++seg) {
      int t = seg >> 1, rr = seg & 1;
      int4 d = *(const int4*)(lds + (rr * 64 + px) * 272 + t * 128 + chg * 16);
      h16* dst = (t ? T2 : T1) + (((size_t)b * 256 + (y0 + rr)) * 256 + (x0 + px)) * 64 + chg * 8;
      *(int4*)dst = d;
    }
  }
}

// ---------------- mega attention: dw convs + means + qkv MFMA + l2norm/scale + MFMA attn + proj ----------------
// grid 2048 flat (XCD-swizzled); 512 thr = 8 waves; TWO adjacent 8x8 windows / block (pipelined).
// LDS overlay: region0 = HALO (dw phases), then x tile INC, then VT.
#define HALO 0       // [10*10 px-rows][64ch] f16 s144 = 14400B (T1 then T2)
#define INC  0       // x tile [px64][ch64] f16 s144 = 9216B, written AFTER halo dies
#define DWW  14400   // dw weights f16 [2][9][64] = 2304B (per-pass stride 1152B)
#define SIN  16704   // sI 64 f32 | sN 64 f32 = 512B
#define INA  17216   // illum tile [px64][ch64] f16 s144 -> later Q -> later AO
#define INB  26432   // noise tile -> later K
// total 35648 B

__global__ __launch_bounds__(512, 8) void k_megaattn(
    const h16* __restrict__ T1g, const h16* __restrict__ T2g,
    const h16* __restrict__ xT, const h16* __restrict__ Wall,
    const float* __restrict__ temp, float* __restrict__ out)
{
  __shared__ __align__(16) char sm[35648];
  const int tid = threadIdx.x;
  const int wv = tid >> 6, lane = tid & 63;
  const int lg = lane >> 4, lr = lane & 15;
  const int wn = wv & 3;            // co-tile (16 co)
  const int wm = wv >> 2;           // px-half (32 px)

  const int u = blockIdx.x;
  const int xcd = u & 7, idx = u >> 3;
  const int flat = xcd * 256 + idx;          // contiguous slab per XCD
  const int fl0 = flat * 2;                  // first window of the pair (wx even)
  const int b = fl0 >> 10, rem = fl0 & 1023;
  const int wy = rem >> 5, wx0 = rem & 31;
  const int y0 = wy * 8;

  // weight fragments for q,k,v,proj GEMMs (wave's co slice = wn*16..+16)
  half8 wf[4][2];
#pragma unroll
  for (int m = 0; m < 4; ++m)
#pragma unroll
    for (int ks = 0; ks < 2; ++ks)
      wf[m][ks] = *(const half8*)(Wall + m * 4096 + (wn * 16 + lr) * 64 + ks * 32 + lg * 8);
  const float thv = temp[wn * 2 + (lg >> 1)];   // temp of head owning channels wn*16+lg*4

  // ---- phase A: issue ALL global loads for BOTH windows ----
  int4 zero4; zero4.x = zero4.y = zero4.z = zero4.w = 0;
  int4 h1r[2][2], h2r[2][2], xtrv[2];
#pragma unroll
  for (int w2 = 0; w2 < 2; ++w2) {
    const int x0w = (wx0 + w2) * 8;
#pragma unroll
    for (int i = 0; i < 2; ++i) {
      int cc = tid + i * 512;
      bool act = cc < 800;
      int prow = act ? (cc >> 3) : 0;
      int c8 = cc & 7;
      int hy = prow / 10, hx = prow - hy * 10;
      int gy = y0 - 1 + hy, gx = x0w - 1 + hx;
      bool ok = act && (unsigned)gy < 256u && (unsigned)gx < 256u;
      size_t ga = (((size_t)b * 256 + gy) * 256 + gx) * (size_t)64 + c8 * 8;
      h1r[w2][i] = ok ? *(const int4*)(T1g + ga) : zero4;
      h2r[w2][i] = ok ? *(const int4*)(T2g + ga) : zero4;
    }
    const size_t wbase = (((size_t)b * 256 + y0) * 256 + x0w) * 64;
    xtrv[w2] = *(const int4*)(xT + wbase + (size_t)(tid >> 6) * 16384 + (tid & 63) * 8);
  }

  // write window-0 T1 halo, dw weights to LDS
#pragma unroll
  for (int i = 0; i < 2; ++i) {
    int cc = tid + i * 512;
    if (cc < 800) *(int4*)(sm + HALO + (cc >> 3) * 144 + (cc & 7) * 16) = h1r[0][i];
  }
  if (tid < 144) {
    int4 d = *(const int4*)(Wall + 16384 + tid * 8);
    *(int4*)(sm + DWW + tid * 16) = d;
  }
  __syncthreads();

  const half8 hz8 = {(h16)0, (h16)0, (h16)0, (h16)0, (h16)0, (h16)0, (h16)0, (h16)0};
  const f32x16 z16 = {0.f,0.f,0.f,0.f,0.f,0.f,0.f,0.f,0.f,0.f,0.f,0.f,0.f,0.f,0.f,0.f};

#pragma unroll
  for (int w2 = 0; w2 < 2; ++w2) {
    const int x0 = (wx0 + w2) * 8;

    // ---- phase B/C/D: depthwise conv (packed f16) T1 -> INA; swap halo; T2 -> INB ----
#pragma unroll
    for (int pass = 0; pass < 2; ++pass) {
      const int outb = pass ? INB : INA;
      {
        const int px = tid >> 3, c8 = tid & 7;   // 512 tasks = 64 px x 8 ch-chunks
        const int py = px >> 3, pxx = px & 7;
        half8 af = hz8;
#pragma unroll
        for (int tap = 0; tap < 9; ++tap) {
          const int dy = tap / 3, dx = tap - dy * 3;
          half8 v  = *(const half8*)(sm + HALO + ((py + dy) * 10 + pxx + dx) * 144 + c8 * 16);
          half8 w8 = *(const half8*)(sm + DWW + pass * 1152 + tap * 128 + c8 * 16);
          af += v * w8;                           // v_pk_fma_f16 x4
        }
        *(half8*)(sm + outb + px * 144 + c8 * 16) = af;
      }
      __syncthreads();
      if (pass == 0) {
        // overwrite halo with T2 of this window
#pragma unroll
        for (int i = 0; i < 2; ++i) {
          int cc = tid + i * 512;
          if (cc < 800) *(int4*)(sm + HALO + (cc >> 3) * 144 + (cc & 7) * 16) = h2r[w2][i];
        }
        __syncthreads();
      }
    }

    // ---- phase E: halo dead -> write x tile into INC overlay; per-pixel channel means ----
    {
      int py = tid >> 6, off = tid & 63;
      int px = py * 8 + (off >> 3);
      *(int4*)(sm + INC + px * 144 + (off & 7) * 16) = xtrv[w2];
    }
    if (tid < 128) {
      int which = tid >> 6, px = tid & 63;
      const char* row = sm + (which ? INB : INA) + px * 144;
      float s = 0.f;
#pragma unroll
      for (int j = 0; j < 8; ++j) {
        half8 v = *(const half8*)(row + j * 16);
#pragma unroll
        for (int e = 0; e < 8; ++e) s += (float)v[e];
      }
      *(float*)(sm + SIN + which * 256 + px * 4) = s * (1.f / 64.f);
    }
    __syncthreads();

    // ---- phase F: q,k,v GEMMs into registers (wave: co tile wn, px half wm) ----
    f32x4 aq[2], ak[2], av[2];
#pragma unroll
    for (int pi = 0; pi < 2; ++pi) {
      aq[pi] = (f32x4){0.f, 0.f, 0.f, 0.f};
      ak[pi] = (f32x4){0.f, 0.f, 0.f, 0.f};
      av[pi] = (f32x4){0.f, 0.f, 0.f, 0.f};
    }
#pragma unroll
    for (int pi = 0; pi < 2; ++pi)
#pragma unroll
      for (int ks = 0; ks < 2; ++ks) {
        const int boff = (wm * 32 + pi * 16 + lr) * 144 + ks * 64 + lg * 16;
        half8 b0 = *(const half8*)(sm + INA + boff);
        half8 b1 = *(const half8*)(sm + INB + boff);
        half8 b2 = *(const half8*)(sm + INC + boff);
        aq[pi] = __builtin_amdgcn_mfma_f32_16x16x32_f16(wf[0][ks], b0, aq[pi], 0, 0, 0);
        ak[pi] = __builtin_amdgcn_mfma_f32_16x16x32_f16(wf[1][ks], b1, ak[pi], 0, 0, 0);
        av[pi] = __builtin_amdgcn_mfma_f32_16x16x32_f16(wf[2][ks], b2, av[pi], 0, 0, 0);
      }
    __syncthreads();   // tile reads done; reuse LDS

    // ---- phase G: normalize/scale, write Q,K ([px][ch]) and VT ([ch][px], INC overlay) ----
#pragma unroll
    for (int pi = 0; pi < 2; ++pi) {
      const int px = wm * 32 + pi * 16 + lr;
      const float si = *(const float*)(sm + SIN + px * 4);
      const float sn = *(const float*)(sm + SIN + 256 + px * 4);
      float s2 = aq[pi][0]*aq[pi][0] + aq[pi][1]*aq[pi][1] + aq[pi][2]*aq[pi][2] + aq[pi][3]*aq[pi][3];
      float qs = (1.f + si) * 0.35355339059327373f * thv /
                 fmaxf(sqrtf(s2 + __shfl_xor(s2, 16)), 1e-12f);
      float k2 = ak[pi][0]*ak[pi][0] + ak[pi][1]*ak[pi][1] + ak[pi][2]*ak[pi][2] + ak[pi][3]*ak[pi][3];
      float ks2 = fminf(fmaxf(1.f - sn, 0.f), 1.f) /
                  fmaxf(sqrtf(k2 + __shfl_xor(k2, 16)), 1e-12f);
      uint2 dq; dq.x = pk2(aq[pi][0]*qs, aq[pi][1]*qs); dq.y = pk2(aq[pi][2]*qs, aq[pi][3]*qs);
      uint2 dk; dk.x = pk2(ak[pi][0]*ks2, ak[pi][1]*ks2); dk.y = pk2(ak[pi][2]*ks2, ak[pi][3]*ks2);
      *(uint2*)(sm + INA + px * 144 + (wn * 16 + lg * 4) * 2) = dq;
      *(uint2*)(sm + INB + px * 144 + (wn * 16 + lg * 4) * 2) = dk;
#pragma unroll
      for (int r = 0; r < 4; ++r)
        *(h16*)(sm + INC + (wn * 16 + lg * 4 + r) * 144 + px * 2) = (h16)av[pi][r];
    }
    __syncthreads();

    // ---- phase H: attention via 32x32x16 MFMA; wave = head wv ----
    const int l31 = lane & 31, hi = lane >> 5;
    {
      const int h = wv;
      half8 kfr[2], qfr[2];
#pragma unroll
      for (int kt = 0; kt < 2; ++kt)
        kfr[kt] = hi ? hz8 : *(const half8*)(sm + INB + (kt * 32 + l31) * 144 + h * 16);
#pragma unroll
      for (int qt = 0; qt < 2; ++qt)
        qfr[qt] = hi ? hz8 : *(const half8*)(sm + INA + (qt * 32 + l31) * 144 + h * 16);

#pragma unroll
      for (int qt = 0; qt < 2; ++qt) {
        f32x16 s0 = __builtin_amdgcn_mfma_f32_32x32x16_f16(kfr[0], qfr[qt], z16, 0, 0, 0);
        f32x16 s1 = __builtin_amdgcn_mfma_f32_32x32x16_f16(kfr[1], qfr[qt], z16, 0, 0, 0);
        float mx = s0[0];
#pragma unroll
        for (int i = 1; i < 16; ++i) mx = fmaxf(mx, s0[i]);
#pragma unroll
        for (int i = 0; i < 16; ++i) mx = fmaxf(mx, s1[i]);
        mx = fmaxf(mx, __shfl_xor(mx, 32));
        float sum = 0.f;
#pragma unroll
        for (int i = 0; i < 16; ++i) { s0[i] = __expf(s0[i] - mx); sum += s0[i]; }
#pragma unroll
        for (int i = 0; i < 16; ++i) { s1[i] = __expf(s1[i] - mx); sum += s1[i]; }
        sum += __shfl_xor(sum, 32);
        const float inv = 1.f / sum;
#pragma unroll
        for (int i = 0; i < 16; ++i) { s0[i] *= inv; s1[i] *= inv; }

        half8 pa[4];
#pragma unroll
        for (int st = 0; st < 4; ++st) {
          const int rb = (st & 1) * 8;
          float p0, p1, p2, p3, p4, p5, p6, p7;
          if (st < 2) {
            p0 = s0[rb+0]; p1 = s0[rb+1]; p2 = s0[rb+2]; p3 = s0[rb+3];
            p4 = s0[rb+4]; p5 = s0[rb+5]; p6 = s0[rb+6]; p7 = s0[rb+7];
          } else {
            p0 = s1[rb+0]; p1 = s1[rb+1]; p2 = s1[rb+2]; p3 = s1[rb+3];
            p4 = s1[rb+4]; p5 = s1[rb+5]; p6 = s1[rb+6]; p7 = s1[rb+7];
          }
          unsigned x0_ = pk2(p0, p1), x1_ = pk2(p2, p3);
          unsigned y0_ = pk2(p4, p5), y1_ = pk2(p6, p7);
          plswap(x0_, y0_);
          plswap(x1_, y1_);
          union { unsigned uu4[4]; half8 h; } uu;
          uu.uu4[0] = x0_; uu.uu4[1] = x1_; uu.uu4[2] = y0_; uu.uu4[3] = y1_;
          pa[st] = uu.h;
        }
        f32x16 oacc = z16;
#pragma unroll
        for (int st = 0; st < 4; ++st) {
          half8 vfr = (l31 < 8)
            ? *(const half8*)(sm + INC + (h * 8 + l31) * 144 + (st * 16 + hi * 8) * 2)
            : hz8;
          oacc = __builtin_amdgcn_mfma_f32_32x32x16_f16(pa[st], vfr, oacc, 0, 0, 0);
        }
        if (l31 < 8) {
#pragma unroll
          for (int r = 0; r < 16; ++r) {
            const int q = qt * 32 + (r & 3) + 8 * (r >> 2) + 4 * hi;
            *(h16*)(sm + INA + q * 144 + (h * 8 + l31) * 2) = (h16)oacc[r];
          }
        }
      }
    }
    __syncthreads();

    // (overlap) stage next window's T1 halo into the now-dead HALO/INC region
    if (w2 == 0) {
#pragma unroll
      for (int i = 0; i < 2; ++i) {
        int cc = tid + i * 512;
        if (cc < 800) *(int4*)(sm + HALO + (cc >> 3) * 144 + (cc & 7) * 16) = h1r[1][i];
      }
    }

    // ---- phase I: output projection (wave: co tile wn, px half wm), fp32 NCHW ----
    f32x4 pacc[2];
#pragma unroll
    for (int pi = 0; pi < 2; ++pi) pacc[pi] = (f32x4){0.f, 0.f, 0.f, 0.f};
#pragma unroll
    for (int pi = 0; pi < 2; ++pi)
#pragma unroll
      for (int ks = 0; ks < 2; ++ks) {
        half8 bfr = *(const half8*)(sm + INA + (wm * 32 + pi * 16 + lr) * 144 + ks * 64 + lg * 16);
        pacc[pi] = __builtin_amdgcn_mfma_f32_16x16x32_f16(wf[3][ks], bfr, pacc[pi], 0, 0, 0);
      }
#pragma unroll
    for (int pi = 0; pi < 2; ++pi) {
      const int px = wm * 32 + pi * 16 + lr;
      const int py = px >> 3, pxx = px & 7;
      const int co = wn * 16 + lg * 4;
      float* ob = out + ((size_t)(b * CC + co)) * HW + (size_t)(y0 + py) * W_ + (x0 + pxx);
      ob[0]      = pacc[pi][0];
      ob[HW]     = pacc[pi][1];
      ob[2 * HW] = pacc[pi][2];
      ob[3 * HW] = pacc[pi][3];
    }

    if (w2 == 0) __syncthreads();   // halo ready + INA reads done before next dw pass
  }
}

extern "C" void kernel_launch(void* const* d_in, const int* in_sizes, int n_in,
                              void* d_out, int out_size, void* d_ws, size_t ws_size,
                              hipStream_t stream) {
  const float* x        = (const float*)d_in[0];
  const float* w_iem    = (const float*)d_in[1];
  const float* w_nem    = (const float*)d_in[2];
  const float* w_iem_dw = (const float*)d_in[3];
  const float* w_nem_dw = (const float*)d_in[4];
  const float* w_q      = (const float*)d_in[5];
  const float* w_k      = (const float*)d_in[6];
  const float* w_v      = (const float*)d_in[7];
  const float* w_proj   = (const float*)d_in[8];
  const float* temp     = (const float*)d_in[9];
  float* outp = (float*)d_out;

  const size_t PLE = (size_t)4 * CC * HW;   // 16,777,216 elems per f16 plane
  h16* h0   = (h16*)d_ws;
  h16* T1   = h0;                           // NHWC f16 sigmoid(conv(x,w_iem))
  h16* T2   = h0 + PLE;
  h16* xT   = h0 + 2 * PLE;
  h16* Bt   = h0 + 3 * PLE;
  h16* Wall = Bt + 73728;

  dim3 b256(256), b512(512);

  k_wprep    <<<dim3(288),        b256, 0, stream>>>(w_iem, w_nem, Bt);
  k_wprep2   <<<dim3(69),         b256, 0, stream>>>(w_q, w_k, w_v, w_proj,
                                                     w_iem_dw, w_nem_dw, Wall);
  k_xpose    <<<dim3(4, 256, 4),  b256, 0, stream>>>(x, xT);
  k_conv3x3x2<<<dim3(4, 128, 4),  b512, 0, stream>>>(xT, Bt, T1, T2);
  k_megaattn <<<dim3(2048),       b512, 0, stream>>>(T1, T2, xT, Wall, temp, outp);
}

// Round 12
// 204.778 us; speedup vs baseline: 1.9225x; 1.9225x over previous
//
#include <hip/hip_runtime.h>
#include <math.h>

#define W_ 256
#define H_ 256
#define HW 65536
#define CC 64

typedef _Float16 h16;
typedef _Float16 half8 __attribute__((ext_vector_type(8)));
typedef float f32x4  __attribute__((ext_vector_type(4)));
typedef float f32x16 __attribute__((ext_vector_type(16)));

__device__ __forceinline__ unsigned pk2(float a, float b) {
  union { h16 h[2]; unsigned u; } c;
  c.h[0] = (h16)a; c.h[1] = (h16)b;
  return c.u;
}
__device__ __forceinline__ void plswap(unsigned &a, unsigned &b) {
  asm volatile("v_permlane32_swap_b32 %0, %1" : "+v"(a), "+v"(b));
}

// ---------------- weight prep: (w_iem,w_nem) fp32 OIHW -> Bt[co128][k=tap*64+ci] f16 ----------------
__global__ __launch_bounds__(256) void k_wprep(
    const float* __restrict__ wi, const float* __restrict__ wn, h16* __restrict__ Bt)
{
  int i = blockIdx.x * 256 + threadIdx.x;
  if (i >= 128 * 576) return;
  int co = i / 576, k = i - co * 576;
  int tap = k >> 6, ci = k & 63;
  const float* src = (co < 64) ? wi : wn;
  int c = co & 63;
  Bt[i] = (h16)src[(c * 64 + ci) * 9 + tap];
}

// ---------------- weight prep 2: wq,wk,wv,wproj -> f16 [4][64][64]; dw weights -> f16 [2][9][64] ----------------
__global__ __launch_bounds__(256) void k_wprep2(
    const float* __restrict__ wq, const float* __restrict__ wk,
    const float* __restrict__ wv, const float* __restrict__ wp,
    const float* __restrict__ wdw1, const float* __restrict__ wdw2,
    h16* __restrict__ W)
{
  int i = blockIdx.x * 256 + threadIdx.x;   // < 17536
  if (i >= 17536) return;
  if (i < 16384) {
    int m = i >> 12, e = i & 4095;
    const float* s = (m == 0) ? wq : (m == 1) ? wk : (m == 2) ? wv : wp;
    W[i] = (h16)s[e];
  } else {
    int e = i - 16384;                       // < 1152
    int pass = e / 576, rem = e - pass * 576;
    int tap = rem >> 6, c = rem & 63;
    const float* s = pass ? wdw2 : wdw1;
    W[i] = (h16)s[c * 9 + tap];
  }
}

// ---------------- x NCHW fp32 -> xT NHWC f16 (streaming transpose) ----------------
// grid (4, 256, 4): xtile(64px) x y x b; 256 thr.
__global__ __launch_bounds__(256) void k_xpose(
    const float* __restrict__ x, h16* __restrict__ xT)
{
  __shared__ __align__(16) char sm[64 * 132];  // [px64][ch66] f16
  const int tid = threadIdx.x;
  const int xt = blockIdx.x, y = blockIdx.y, b = blockIdx.z;
  const int x0 = xt * 64;
  const float* xb = x + ((size_t)b * CC) * HW + y * W_ + x0;
  const int ci = tid >> 2, q = tid & 3;
#pragma unroll
  for (int k = 0; k < 4; ++k) {
    const int pc = q + k * 4;                // px-chunk (4 px each), 0..15
    float4 v = *(const float4*)(xb + (size_t)ci * HW + pc * 4);
    const int px = pc * 4;
    *(h16*)(sm + (px + 0) * 132 + ci * 2) = (h16)v.x;
    *(h16*)(sm + (px + 1) * 132 + ci * 2) = (h16)v.y;
    *(h16*)(sm + (px + 2) * 132 + ci * 2) = (h16)v.z;
    *(h16*)(sm + (px + 3) * 132 + ci * 2) = (h16)v.w;
  }
  __syncthreads();
  h16* dst = xT + (((size_t)b * 256 + y) * 256 + x0) * 64;
#pragma unroll
  for (int it = 0; it < 2; ++it) {
    int task = tid + it * 256;
    int px = task >> 3, c8 = task & 7;
    int4 d = *(const int4*)(sm + px * 132 + c8 * 16);
    *(int4*)(dst + px * 64 + c8 * 8) = d;
  }
}

// ---------------- fused dual conv3x3 + sigmoid (MFMA f16), input xT NHWC f16 ----------------
// grid (4, 128, 4). block 512 = 8 waves (4 co-waves x 2 px-waves).
__global__ __launch_bounds__(512) void k_conv3x3x2(
    const h16* __restrict__ xT, const h16* __restrict__ Bt,
    h16* __restrict__ T1, h16* __restrict__ T2)
{
  __shared__ __align__(16) char lds[38016];

  const int tid = threadIdx.x;
  const int b = blockIdx.z, ry = blockIdx.y, cx = blockIdx.x;
  const int y0 = ry * 2, x0 = cx * 64;

  // ---- stage xT tile: rows y0-1..y0+2, cols x0-1..x0+64, 64 ch; LDS [pxr 264][ch64] s144 ----
  {
    const h16* xb = xT + ((size_t)b * 256) * 256 * 64;
    int4 zero4; zero4.x = zero4.y = zero4.z = zero4.w = 0;
#pragma unroll
    for (int it = 0; it < 5; ++it) {
      int idx = tid + it * 512;
      if (idx < 2112) {                       // 264 px-rows x 8 chunks
        int pxr = idx >> 3, c8 = idx & 7;
        int r = pxr / 66, c = pxr - r * 66;
        int gy = y0 - 1 + r, gx = x0 - 1 + c;
        int4 d = zero4;
        if ((unsigned)gy < 256u && (unsigned)gx < 256u)
          d = *(const int4*)(xb + ((size_t)(gy * 256 + gx)) * 64 + c8 * 8);
        *(int4*)(lds + pxr * 144 + c8 * 16) = d;
      }
    }
  }
  __syncthreads();

  const int wv = tid >> 6, lane = tid & 63;
  const int wn_ = wv & 3;
  const int wm_ = wv >> 2;
  const int cob = wn_ * 32;
  const int pxb = wm_ * 64;
  const int lg = lane >> 4, lr = lane & 15;

  const char* pB[4];
#pragma unroll
  for (int pi = 0; pi < 4; ++pi) {
    int opx = (pxb + pi * 16 + lr) & 63;
    pB[pi] = lds + (wm_ * 66 + opx) * 144 + lg * 16;
  }
  const h16* wb0 = Bt + (size_t)(cob + lr) * 576 + lg * 8;
  const h16* wb1 = wb0 + 16 * 576;

  f32x4 acc[2][4];
#pragma unroll
  for (int i = 0; i < 2; ++i)
#pragma unroll
    for (int j = 0; j < 4; ++j) acc[i][j] = (f32x4){0.f, 0.f, 0.f, 0.f};

#pragma unroll
  for (int tap = 0; tap < 9; ++tap) {
    const int dy = tap / 3, dx = tap - dy * 3;
#pragma unroll
    for (int kh = 0; kh < 2; ++kh) {
      const int loff = (dy * 66 + dx) * 144 + kh * 64;
      const int koff = tap * 64 + kh * 32;
      half8 a0 = *(const half8*)(wb0 + koff);
      half8 a1 = *(const half8*)(wb1 + koff);
      half8 b0 = *(const half8*)(pB[0] + loff);
      half8 b1 = *(const half8*)(pB[1] + loff);
      half8 b2 = *(const half8*)(pB[2] + loff);
      half8 b3 = *(const half8*)(pB[3] + loff);
      acc[0][0] = __builtin_amdgcn_mfma_f32_16x16x32_f16(a0, b0, acc[0][0], 0, 0, 0);
      acc[0][1] = __builtin_amdgcn_mfma_f32_16x16x32_f16(a0, b1, acc[0][1], 0, 0, 0);
      acc[0][2] = __builtin_amdgcn_mfma_f32_16x16x32_f16(a0, b2, acc[0][2], 0, 0, 0);
      acc[0][3] = __builtin_amdgcn_mfma_f32_16x16x32_f16(a0, b3, acc[0][3], 0, 0, 0);
      acc[1][0] = __builtin_amdgcn_mfma_f32_16x16x32_f16(a1, b0, acc[1][0], 0, 0, 0);
      acc[1][1] = __builtin_amdgcn_mfma_f32_16x16x32_f16(a1, b1, acc[1][1], 0, 0, 0);
      acc[1][2] = __builtin_amdgcn_mfma_f32_16x16x32_f16(a1, b2, acc[1][2], 0, 0, 0);
      acc[1][3] = __builtin_amdgcn_mfma_f32_16x16x32_f16(a1, b3, acc[1][3], 0, 0, 0);
    }
  }
  __syncthreads();   // input tile dead; reuse LDS for output transpose

  // write sigmoid(acc) to LDS O[px 128][co 128] f16, stride 272B
#pragma unroll
  for (int ni = 0; ni < 2; ++ni) {
#pragma unroll
    for (int pi = 0; pi < 4; ++pi) {
      const int opx = (pxb + pi * 16 + lr) & 63;
      const int pxid = wm_ * 64 + opx;
      const int co = cob + ni * 16 + lg * 4;
      float s0 = 1.f / (1.f + __expf(-acc[ni][pi][0]));
      float s1 = 1.f / (1.f + __expf(-acc[ni][pi][1]));
      float s2 = 1.f / (1.f + __expf(-acc[ni][pi][2]));
      float s3 = 1.f / (1.f + __expf(-acc[ni][pi][3]));
      uint2 d; d.x = pk2(s0, s1); d.y = pk2(s2, s3);
      *(uint2*)(lds + pxid * 272 + co * 2) = d;
    }
  }
  __syncthreads();

  {
    int px = tid >> 3, chg = tid & 7;
#pragma unroll
    for (int seg = 0; seg < 4; ++seg) {
      int t = seg >> 1, rr = seg & 1;
      int4 d = *(const int4*)(lds + (rr * 64 + px) * 272 + t * 128 + chg * 16);
      h16* dst = (t ? T2 : T1) + (((size_t)b * 256 + (y0 + rr)) * 256 + (x0 + px)) * 64 + chg * 8;
      *(int4*)dst = d;
    }
  }
}

// ---------------- mega attention: dw convs + means + qkv MFMA + l2norm/scale + MFMA attn + proj ----------------
// grid 4096 flat (XCD-swizzled); 512 thr = 8 waves; one 8x8 window / block; wave = head.
#define HALO 0       // [10*10 px-rows][64ch] f16 s144 = 14400B (T1 then T2)
#define DWW  14400   // dw weights f16 [2][9][64] = 2304B (per-pass stride 1152B)
#define SIN  16704   // sI 64 f32 | sN 64 f32 = 512B
#define INA  17216   // illum tile [px64][ch64] f16 s144 -> later Q -> later AO
#define INB  26432   // noise tile -> later K
#define INC  35648   // x tile     -> later VT [ch64][px64] s144
// total 44864 B -> 3 blocks/CU

__global__ __launch_bounds__(512, 6) void k_megaattn(
    const h16* __restrict__ T1g, const h16* __restrict__ T2g,
    const h16* __restrict__ xT, const h16* __restrict__ Wall,
    const float* __restrict__ temp, float* __restrict__ out)
{
  __shared__ __align__(16) char sm[44864];
  const int tid = threadIdx.x;
  const int wv = tid >> 6, lane = tid & 63;
  const int lg = lane >> 4, lr = lane & 15;
  const int wn = wv & 3;            // co-tile (16 co)
  const int wm = wv >> 2;           // px-half (32 px)

  const int u = blockIdx.x;
  const int xcd = u & 7, idx = u >> 3;
  const int flat = xcd * 512 + idx;          // contiguous slab per XCD
  const int b = flat >> 10, rem = flat & 1023;
  const int wy = rem >> 5, wx = rem & 31;
  const int y0 = wy * 8, x0 = wx * 8;

  // weight fragments for q,k,v,proj GEMMs (wave's co slice = wn*16..+16)
  half8 wf[4][2];
#pragma unroll
  for (int m = 0; m < 4; ++m)
#pragma unroll
    for (int ks = 0; ks < 2; ++ks)
      wf[m][ks] = *(const half8*)(Wall + m * 4096 + (wn * 16 + lr) * 64 + ks * 32 + lg * 8);
  const float thv = temp[wn * 2 + (lg >> 1)];   // temp of head owning channels wn*16+lg*4

  // ---- phase A: issue halo loads (T1+T2) to regs, x tile to regs, dw weights ----
  int4 zero4; zero4.x = zero4.y = zero4.z = zero4.w = 0;
  int4 h1r[2], h2r[2], xtr;
#pragma unroll
  for (int i = 0; i < 2; ++i) {
    int cc = tid + i * 512;
    bool act = cc < 800;
    int prow = act ? (cc >> 3) : 0;
    int c8 = cc & 7;
    int hy = prow / 10, hx = prow - hy * 10;
    int gy = y0 - 1 + hy, gx = x0 - 1 + hx;
    bool ok = act && (unsigned)gy < 256u && (unsigned)gx < 256u;
    size_t ga = (((size_t)b * 256 + gy) * 256 + gx) * (size_t)64 + c8 * 8;
    h1r[i] = ok ? *(const int4*)(T1g + ga) : zero4;
    h2r[i] = ok ? *(const int4*)(T2g + ga) : zero4;
  }
  const size_t wbase = (((size_t)b * 256 + y0) * 256 + x0) * 64;
  xtr = *(const int4*)(xT + wbase + (size_t)(tid >> 6) * 16384 + (tid & 63) * 8);

  // write T1 halo, x tile, dw weights to LDS
#pragma unroll
  for (int i = 0; i < 2; ++i) {
    int cc = tid + i * 512;
    if (cc < 800) *(int4*)(sm + HALO + (cc >> 3) * 144 + (cc & 7) * 16) = h1r[i];
  }
  {
    int py = tid >> 6, off = tid & 63;
    int px = py * 8 + (off >> 3);
    *(int4*)(sm + INC + px * 144 + (off & 7) * 16) = xtr;
  }
  if (tid < 144) {
    int4 d = *(const int4*)(Wall + 16384 + tid * 8);
    *(int4*)(sm + DWW + tid * 16) = d;
  }
  __syncthreads();

  // ---- phase B/C/D: depthwise conv (packed f16) T1 -> INA; swap halo; T2 -> INB ----
  const half8 hz8 = {(h16)0, (h16)0, (h16)0, (h16)0, (h16)0, (h16)0, (h16)0, (h16)0};
#pragma unroll
  for (int pass = 0; pass < 2; ++pass) {
    const int outb = pass ? INB : INA;
    {
      const int px = tid >> 3, c8 = tid & 7;   // 512 tasks = 64 px x 8 ch-chunks
      const int py = px >> 3, pxx = px & 7;
      half8 af = hz8;
#pragma unroll
      for (int tap = 0; tap < 9; ++tap) {
        const int dy = tap / 3, dx = tap - dy * 3;
        half8 v  = *(const half8*)(sm + HALO + ((py + dy) * 10 + pxx + dx) * 144 + c8 * 16);
        half8 w8 = *(const half8*)(sm + DWW + pass * 1152 + tap * 128 + c8 * 16);
        af += v * w8;                           // v_pk_fma_f16 x4
      }
      *(half8*)(sm + outb + px * 144 + c8 * 16) = af;
    }
    __syncthreads();
    if (pass == 0) {
      // overwrite halo with T2
#pragma unroll
      for (int i = 0; i < 2; ++i) {
        int cc = tid + i * 512;
        if (cc < 800) *(int4*)(sm + HALO + (cc >> 3) * 144 + (cc & 7) * 16) = h2r[i];
      }
      __syncthreads();
    }
  }

  // ---- phase E: per-pixel channel means ----
  if (tid < 128) {
    int which = tid >> 6, px = tid & 63;
    const char* row = sm + (which ? INB : INA) + px * 144;
    float s = 0.f;
#pragma unroll
    for (int j = 0; j < 8; ++j) {
      half8 v = *(const half8*)(row + j * 16);
#pragma unroll
      for (int e = 0; e < 8; ++e) s += (float)v[e];
    }
    *(float*)(sm + SIN + which * 256 + px * 4) = s * (1.f / 64.f);
  }
  __syncthreads();

  // ---- phase F: q,k,v GEMMs into registers (wave: co tile wn, px half wm) ----
  f32x4 aq[2], ak[2], av[2];
#pragma unroll
  for (int pi = 0; pi < 2; ++pi) {
    aq[pi] = (f32x4){0.f, 0.f, 0.f, 0.f};
    ak[pi] = (f32x4){0.f, 0.f, 0.f, 0.f};
    av[pi] = (f32x4){0.f, 0.f, 0.f, 0.f};
  }
  __builtin_amdgcn_s_setprio(1);
#pragma unroll
  for (int pi = 0; pi < 2; ++pi)
#pragma unroll
    for (int ks = 0; ks < 2; ++ks) {
      const int boff = (wm * 32 + pi * 16 + lr) * 144 + ks * 64 + lg * 16;
      half8 b0 = *(const half8*)(sm + INA + boff);
      half8 b1 = *(const half8*)(sm + INB + boff);
      half8 b2 = *(const half8*)(sm + INC + boff);
      aq[pi] = __builtin_amdgcn_mfma_f32_16x16x32_f16(wf[0][ks], b0, aq[pi], 0, 0, 0);
      ak[pi] = __builtin_amdgcn_mfma_f32_16x16x32_f16(wf[1][ks], b1, ak[pi], 0, 0, 0);
      av[pi] = __builtin_amdgcn_mfma_f32_16x16x32_f16(wf[2][ks], b2, av[pi], 0, 0, 0);
    }
  __builtin_amdgcn_s_setprio(0);
  __syncthreads();   // tile reads done; reuse LDS

  // ---- phase G: normalize/scale, write Q,K ([px][ch]) and VT ([ch][px]) ----
#pragma unroll
  for (int pi = 0; pi < 2; ++pi) {
    const int px = wm * 32 + pi * 16 + lr;
    const float si = *(const float*)(sm + SIN + px * 4);
    const float sn = *(const float*)(sm + SIN + 256 + px * 4);
    float s2 = aq[pi][0]*aq[pi][0] + aq[pi][1]*aq[pi][1] + aq[pi][2]*aq[pi][2] + aq[pi][3]*aq[pi][3];
    float qs = (1.f + si) * 0.35355339059327373f * thv /
               fmaxf(sqrtf(s2 + __shfl_xor(s2, 16)), 1e-12f);
    float k2 = ak[pi][0]*ak[pi][0] + ak[pi][1]*ak[pi][1] + ak[pi][2]*ak[pi][2] + ak[pi][3]*ak[pi][3];
    float ks2 = fminf(fmaxf(1.f - sn, 0.f), 1.f) /
                fmaxf(sqrtf(k2 + __shfl_xor(k2, 16)), 1e-12f);
    uint2 dq; dq.x = pk2(aq[pi][0]*qs, aq[pi][1]*qs); dq.y = pk2(aq[pi][2]*qs, aq[pi][3]*qs);
    uint2 dk; dk.x = pk2(ak[pi][0]*ks2, ak[pi][1]*ks2); dk.y = pk2(ak[pi][2]*ks2, ak[pi][3]*ks2);
    *(uint2*)(sm + INA + px * 144 + (wn * 16 + lg * 4) * 2) = dq;
    *(uint2*)(sm + INB + px * 144 + (wn * 16 + lg * 4) * 2) = dk;
#pragma unroll
    for (int r = 0; r < 4; ++r)
      *(h16*)(sm + INC + (wn * 16 + lg * 4 + r) * 144 + px * 2) = (h16)av[pi][r];
  }
  __syncthreads();

  // ---- phase H: attention via 32x32x16 MFMA; wave = head wv ----
  const int l31 = lane & 31, hi = lane >> 5;
  const half8 hz = hz8;
  const f32x16 z16 = {0.f,0.f,0.f,0.f,0.f,0.f,0.f,0.f,0.f,0.f,0.f,0.f,0.f,0.f,0.f,0.f};
  {
    const int h = wv;
    half8 kfr[2], qfr[2];
#pragma unroll
    for (int kt = 0; kt < 2; ++kt)
      kfr[kt] = hi ? hz : *(const half8*)(sm + INB + (kt * 32 + l31) * 144 + h * 16);
#pragma unroll
    for (int qt = 0; qt < 2; ++qt)
      qfr[qt] = hi ? hz : *(const half8*)(sm + INA + (qt * 32 + l31) * 144 + h * 16);

#pragma unroll
    for (int qt = 0; qt < 2; ++qt) {
      __builtin_amdgcn_s_setprio(1);
      f32x16 s0 = __builtin_amdgcn_mfma_f32_32x32x16_f16(kfr[0], qfr[qt], z16, 0, 0, 0);
      f32x16 s1 = __builtin_amdgcn_mfma_f32_32x32x16_f16(kfr[1], qfr[qt], z16, 0, 0, 0);
      __builtin_amdgcn_s_setprio(0);
      float mx = s0[0];
#pragma unroll
      for (int i = 1; i < 16; ++i) mx = fmaxf(mx, s0[i]);
#pragma unroll
      for (int i = 0; i < 16; ++i) mx = fmaxf(mx, s1[i]);
      mx = fmaxf(mx, __shfl_xor(mx, 32));
      float sum = 0.f;
#pragma unroll
      for (int i = 0; i < 16; ++i) { s0[i] = __expf(s0[i] - mx); sum += s0[i]; }
#pragma unroll
      for (int i = 0; i < 16; ++i) { s1[i] = __expf(s1[i] - mx); sum += s1[i]; }
      sum += __shfl_xor(sum, 32);
      const float inv = 1.f / sum;
#pragma unroll
      for (int i = 0; i < 16; ++i) { s0[i] *= inv; s1[i] *= inv; }

      half8 pa[4];
#pragma unroll
      for (int st = 0; st < 4; ++st) {
        const int rb = (st & 1) * 8;
        float p0, p1, p2, p3, p4, p5, p6, p7;
        if (st < 2) {
          p0 = s0[rb+0]; p1 = s0[rb+1]; p2 = s0[rb+2]; p3 = s0[rb+3];
          p4 = s0[rb+4]; p5 = s0[rb+5]; p6 = s0[rb+6]; p7 = s0[rb+7];
        } else {
          p0 = s1[rb+0]; p1 = s1[rb+1]; p2 = s1[rb+2]; p3 = s1[rb+3];
          p4 = s1[rb+4]; p5 = s1[rb+5]; p6 = s1[rb+6]; p7 = s1[rb+7];
        }
        unsigned x0_ = pk2(p0, p1), x1_ = pk2(p2, p3);
        unsigned y0_ = pk2(p4, p5), y1_ = pk2(p6, p7);
        plswap(x0_, y0_);
        plswap(x1_, y1_);
        union { unsigned uu4[4]; half8 h; } uu;
        uu.uu4[0] = x0_; uu.uu4[1] = x1_; uu.uu4[2] = y0_; uu.uu4[3] = y1_;
        pa[st] = uu.h;
      }
      f32x16 oacc = z16;
      __builtin_amdgcn_s_setprio(1);
#pragma unroll
      for (int st = 0; st < 4; ++st) {
        half8 vfr = (l31 < 8)
          ? *(const half8*)(sm + INC + (h * 8 + l31) * 144 + (st * 16 + hi * 8) * 2)
          : hz;
        oacc = __builtin_amdgcn_mfma_f32_32x32x16_f16(pa[st], vfr, oacc, 0, 0, 0);
      }
      __builtin_amdgcn_s_setprio(0);
      if (l31 < 8) {
#pragma unroll
        for (int r = 0; r < 16; ++r) {
          const int q = qt * 32 + (r & 3) + 8 * (r >> 2) + 4 * hi;
          *(h16*)(sm + INA + q * 144 + (h * 8 + l31) * 2) = (h16)oacc[r];
        }
      }
    }
  }
  __syncthreads();

  // ---- phase I: output projection (wave: co tile wn, px half wm) ----
  f32x4 pacc[2];
#pragma unroll
  for (int pi = 0; pi < 2; ++pi) pacc[pi] = (f32x4){0.f, 0.f, 0.f, 0.f};
  __builtin_amdgcn_s_setprio(1);
#pragma unroll
  for (int pi = 0; pi < 2; ++pi)
#pragma unroll
    for (int ks = 0; ks < 2; ++ks) {
      half8 bfr = *(const half8*)(sm + INA + (wm * 32 + pi * 16 + lr) * 144 + ks * 64 + lg * 16);
      pacc[pi] = __builtin_amdgcn_mfma_f32_16x16x32_f16(wf[3][ks], bfr, pacc[pi], 0, 0, 0);
    }
  __builtin_amdgcn_s_setprio(0);
#pragma unroll
  for (int pi = 0; pi < 2; ++pi) {
    const int px = wm * 32 + pi * 16 + lr;
    const int py = px >> 3, pxx = px & 7;
    const int co = wn * 16 + lg * 4;
    float* ob = out + ((size_t)(b * CC + co)) * HW + (size_t)(y0 + py) * W_ + (x0 + pxx);
    ob[0]      = pacc[pi][0];
    ob[HW]     = pacc[pi][1];
    ob[2 * HW] = pacc[pi][2];
    ob[3 * HW] = pacc[pi][3];
  }
}

extern "C" void kernel_launch(void* const* d_in, const int* in_sizes, int n_in,
                              void* d_out, int out_size, void* d_ws, size_t ws_size,
                              hipStream_t stream) {
  const float* x        = (const float*)d_in[0];
  const float* w_iem    = (const float*)d_in[1];
  const float* w_nem    = (const float*)d_in[2];
  const float* w_iem_dw = (const float*)d_in[3];
  const float* w_nem_dw = (const float*)d_in[4];
  const float* w_q      = (const float*)d_in[5];
  const float* w_k      = (const float*)d_in[6];
  const float* w_v      = (const float*)d_in[7];
  const float* w_proj   = (const float*)d_in[8];
  const float* temp     = (const float*)d_in[9];
  float* outp = (float*)d_out;

  const size_t PLE = (size_t)4 * CC * HW;   // 16,777,216 elems per f16 plane
  h16* h0   = (h16*)d_ws;
  h16* T1   = h0;                           // NHWC f16 sigmoid(conv(x,w_iem))
  h16* T2   = h0 + PLE;
  h16* xT   = h0 + 2 * PLE;
  h16* Bt   = h0 + 3 * PLE;
  h16* Wall = Bt + 73728;

  dim3 b256(256), b512(512);

  k_wprep    <<<dim3(288),        b256, 0, stream>>>(w_iem, w_nem, Bt);
  k_wprep2   <<<dim3(69),         b256, 0, stream>>>(w_q, w_k, w_v, w_proj,
                                                     w_iem_dw, w_nem_dw, Wall);
  k_xpose    <<<dim3(4, 256, 4),  b256, 0, stream>>>(x, xT);
  k_conv3x3x2<<<dim3(4, 128, 4),  b512, 0, stream>>>(xT, Bt, T1, T2);
  k_megaattn <<<dim3(4096),       b512, 0, stream>>>(T1, T2, xT, Wall, temp, outp);
}

// Round 13
// 192.006 us; speedup vs baseline: 2.0504x; 1.0665x over previous
//
#include <hip/hip_runtime.h>
#include <math.h>

#define W_ 256
#define H_ 256
#define HW 65536
#define CC 64

typedef _Float16 h16;
typedef _Float16 half8 __attribute__((ext_vector_type(8)));
typedef float f32x4  __attribute__((ext_vector_type(4)));
typedef float f32x16 __attribute__((ext_vector_type(16)));

__device__ __forceinline__ unsigned pk2(float a, float b) {
  union { h16 h[2]; unsigned u; } c;
  c.h[0] = (h16)a; c.h[1] = (h16)b;
  return c.u;
}
__device__ __forceinline__ void plswap(unsigned &a, unsigned &b) {
  asm volatile("v_permlane32_swap_b32 %0, %1" : "+v"(a), "+v"(b));
}

// ---------------- weight prep: (w_iem,w_nem) fp32 OIHW -> Bt[co128][k=tap*64+ci] f16 ----------------
__global__ __launch_bounds__(256) void k_wprep(
    const float* __restrict__ wi, const float* __restrict__ wn, h16* __restrict__ Bt)
{
  int i = blockIdx.x * 256 + threadIdx.x;
  if (i >= 128 * 576) return;
  int co = i / 576, k = i - co * 576;
  int tap = k >> 6, ci = k & 63;
  const float* src = (co < 64) ? wi : wn;
  int c = co & 63;
  Bt[i] = (h16)src[(c * 64 + ci) * 9 + tap];
}

// ---------------- weight prep 2: wq,wk,wv,wproj -> f16 [4][64][64]; dw weights -> f16 [2][9][64] ----------------
__global__ __launch_bounds__(256) void k_wprep2(
    const float* __restrict__ wq, const float* __restrict__ wk,
    const float* __restrict__ wv, const float* __restrict__ wp,
    const float* __restrict__ wdw1, const float* __restrict__ wdw2,
    h16* __restrict__ W)
{
  int i = blockIdx.x * 256 + threadIdx.x;   // < 17536
  if (i >= 17536) return;
  if (i < 16384) {
    int m = i >> 12, e = i & 4095;
    const float* s = (m == 0) ? wq : (m == 1) ? wk : (m == 2) ? wv : wp;
    W[i] = (h16)s[e];
  } else {
    int e = i - 16384;                       // < 1152
    int pass = e / 576, rem = e - pass * 576;
    int tap = rem >> 6, c = rem & 63;
    const float* s = pass ? wdw2 : wdw1;
    W[i] = (h16)s[c * 9 + tap];
  }
}

// ---------------- x NCHW fp32 -> xT NHWC f16 (streaming transpose) ----------------
// grid (4, 256, 4): xtile(64px) x y x b; 256 thr.
__global__ __launch_bounds__(256) void k_xpose(
    const float* __restrict__ x, h16* __restrict__ xT)
{
  __shared__ __align__(16) char sm[64 * 132];  // [px64][ch66] f16
  const int tid = threadIdx.x;
  const int xt = blockIdx.x, y = blockIdx.y, b = blockIdx.z;
  const int x0 = xt * 64;
  const float* xb = x + ((size_t)b * CC) * HW + y * W_ + x0;
  const int ci = tid >> 2, q = tid & 3;
#pragma unroll
  for (int k = 0; k < 4; ++k) {
    const int pc = q + k * 4;                // px-chunk (4 px each), 0..15
    float4 v = *(const float4*)(xb + (size_t)ci * HW + pc * 4);
    const int px = pc * 4;
    *(h16*)(sm + (px + 0) * 132 + ci * 2) = (h16)v.x;
    *(h16*)(sm + (px + 1) * 132 + ci * 2) = (h16)v.y;
    *(h16*)(sm + (px + 2) * 132 + ci * 2) = (h16)v.z;
    *(h16*)(sm + (px + 3) * 132 + ci * 2) = (h16)v.w;
  }
  __syncthreads();
  h16* dst = xT + (((size_t)b * 256 + y) * 256 + x0) * 64;
#pragma unroll
  for (int it = 0; it < 2; ++it) {
    int task = tid + it * 256;
    int px = task >> 3, c8 = task & 7;
    int4 d = *(const int4*)(sm + px * 132 + c8 * 16);
    *(int4*)(dst + px * 64 + c8 * 8) = d;
  }
}

// ---------------- fused dual conv3x3 + sigmoid (MFMA f16), input xT NHWC f16 ----------------
// grid (4, 128, 4). block 512 = 8 waves (4 co-waves x 2 px-waves).
__global__ __launch_bounds__(512) void k_conv3x3x2(
    const h16* __restrict__ xT, const h16* __restrict__ Bt,
    h16* __restrict__ T1, h16* __restrict__ T2)
{
  __shared__ __align__(16) char lds[38016];

  const int tid = threadIdx.x;
  const int b = blockIdx.z, ry = blockIdx.y, cx = blockIdx.x;
  const int y0 = ry * 2, x0 = cx * 64;

  // ---- stage xT tile: rows y0-1..y0+2, cols x0-1..x0+64, 64 ch; LDS [pxr 264][ch64] s144 ----
  {
    const h16* xb = xT + ((size_t)b * 256) * 256 * 64;
    int4 zero4; zero4.x = zero4.y = zero4.z = zero4.w = 0;
#pragma unroll
    for (int it = 0; it < 5; ++it) {
      int idx = tid + it * 512;
      if (idx < 2112) {                       // 264 px-rows x 8 chunks
        int pxr = idx >> 3, c8 = idx & 7;
        int r = pxr / 66, c = pxr - r * 66;
        int gy = y0 - 1 + r, gx = x0 - 1 + c;
        int4 d = zero4;
        if ((unsigned)gy < 256u && (unsigned)gx < 256u)
          d = *(const int4*)(xb + ((size_t)(gy * 256 + gx)) * 64 + c8 * 8);
        *(int4*)(lds + pxr * 144 + c8 * 16) = d;
      }
    }
  }
  __syncthreads();

  const int wv = tid >> 6, lane = tid & 63;
  const int wn_ = wv & 3;
  const int wm_ = wv >> 2;
  const int cob = wn_ * 32;
  const int pxb = wm_ * 64;
  const int lg = lane >> 4, lr = lane & 15;

  const char* pB[4];
#pragma unroll
  for (int pi = 0; pi < 4; ++pi) {
    int opx = (pxb + pi * 16 + lr) & 63;
    pB[pi] = lds + (wm_ * 66 + opx) * 144 + lg * 16;
  }
  const h16* wb0 = Bt + (size_t)(cob + lr) * 576 + lg * 8;
  const h16* wb1 = wb0 + 16 * 576;

  f32x4 acc[2][4];
#pragma unroll
  for (int i = 0; i < 2; ++i)
#pragma unroll
    for (int j = 0; j < 4; ++j) acc[i][j] = (f32x4){0.f, 0.f, 0.f, 0.f};

#pragma unroll
  for (int tap = 0; tap < 9; ++tap) {
    const int dy = tap / 3, dx = tap - dy * 3;
#pragma unroll
    for (int kh = 0; kh < 2; ++kh) {
      const int loff = (dy * 66 + dx) * 144 + kh * 64;
      const int koff = tap * 64 + kh * 32;
      half8 a0 = *(const half8*)(wb0 + koff);
      half8 a1 = *(const half8*)(wb1 + koff);
      half8 b0 = *(const half8*)(pB[0] + loff);
      half8 b1 = *(const half8*)(pB[1] + loff);
      half8 b2 = *(const half8*)(pB[2] + loff);
      half8 b3 = *(const half8*)(pB[3] + loff);
      acc[0][0] = __builtin_amdgcn_mfma_f32_16x16x32_f16(a0, b0, acc[0][0], 0, 0, 0);
      acc[0][1] = __builtin_amdgcn_mfma_f32_16x16x32_f16(a0, b1, acc[0][1], 0, 0, 0);
      acc[0][2] = __builtin_amdgcn_mfma_f32_16x16x32_f16(a0, b2, acc[0][2], 0, 0, 0);
      acc[0][3] = __builtin_amdgcn_mfma_f32_16x16x32_f16(a0, b3, acc[0][3], 0, 0, 0);
      acc[1][0] = __builtin_amdgcn_mfma_f32_16x16x32_f16(a1, b0, acc[1][0], 0, 0, 0);
      acc[1][1] = __builtin_amdgcn_mfma_f32_16x16x32_f16(a1, b1, acc[1][1], 0, 0, 0);
      acc[1][2] = __builtin_amdgcn_mfma_f32_16x16x32_f16(a1, b2, acc[1][2], 0, 0, 0);
      acc[1][3] = __builtin_amdgcn_mfma_f32_16x16x32_f16(a1, b3, acc[1][3], 0, 0, 0);
    }
  }
  __syncthreads();   // input tile dead; reuse LDS for output transpose

  // write sigmoid(acc) to LDS O[px 128][co 128] f16, stride 272B
#pragma unroll
  for (int ni = 0; ni < 2; ++ni) {
#pragma unroll
    for (int pi = 0; pi < 4; ++pi) {
      const int opx = (pxb + pi * 16 + lr) & 63;
      const int pxid = wm_ * 64 + opx;
      const int co = cob + ni * 16 + lg * 4;
      float s0 = 1.f / (1.f + __expf(-acc[ni][pi][0]));
      float s1 = 1.f / (1.f + __expf(-acc[ni][pi][1]));
      float s2 = 1.f / (1.f + __expf(-acc[ni][pi][2]));
      float s3 = 1.f / (1.f + __expf(-acc[ni][pi][3]));
      uint2 d; d.x = pk2(s0, s1); d.y = pk2(s2, s3);
      *(uint2*)(lds + pxid * 272 + co * 2) = d;
    }
  }
  __syncthreads();

  {
    int px = tid >> 3, chg = tid & 7;
#pragma unroll
    for (int seg = 0; seg < 4; ++seg) {
      int t = seg >> 1, rr = seg & 1;
      int4 d = *(const int4*)(lds + (rr * 64 + px) * 272 + t * 128 + chg * 16);
      h16* dst = (t ? T2 : T1) + (((size_t)b * 256 + (y0 + rr)) * 256 + (x0 + px)) * 64 + chg * 8;
      *(int4*)dst = d;
    }
  }
}

// ---------------- mega attention: dw convs (+fused means) + qkv MFMA + l2norm/scale + MFMA attn + proj ----------------
// grid 4096 flat (XCD-swizzled); 512 thr = 8 waves; one 8x8 window / block; wave = head.
#define HALO 0       // [10*10 px-rows][64ch] f16 s144 = 14400B (T1 then T2)
#define DWW  14400   // dw weights f16 [2][9][64] = 2304B (per-pass stride 1152B)
#define SIN  16704   // sI 64 f32 | sN 64 f32 = 512B
#define INA  17216   // illum tile [px64][ch64] f16 s144 -> later Q -> later AO
#define INB  26432   // noise tile -> later K
#define INC  35648   // x tile     -> later VT [ch64][px64] s144
// total 44864 B -> 3 blocks/CU

__global__ __launch_bounds__(512, 6) void k_megaattn(
    const h16* __restrict__ T1g, const h16* __restrict__ T2g,
    const h16* __restrict__ xT, const h16* __restrict__ Wall,
    const float* __restrict__ temp, float* __restrict__ out)
{
  __shared__ __align__(16) char sm[44864];
  const int tid = threadIdx.x;
  const int wv = tid >> 6, lane = tid & 63;
  const int lg = lane >> 4, lr = lane & 15;
  const int wn = wv & 3;            // co-tile (16 co)
  const int wm = wv >> 2;           // px-half (32 px)

  const int u = blockIdx.x;
  const int xcd = u & 7, idx = u >> 3;
  const int flat = xcd * 512 + idx;          // contiguous slab per XCD
  const int b = flat >> 10, rem = flat & 1023;
  const int wy = rem >> 5, wx = rem & 31;
  const int y0 = wy * 8, x0 = wx * 8;

  // weight fragments for q,k,v,proj GEMMs (wave's co slice = wn*16..+16)
  half8 wf[4][2];
#pragma unroll
  for (int m = 0; m < 4; ++m)
#pragma unroll
    for (int ks = 0; ks < 2; ++ks)
      wf[m][ks] = *(const half8*)(Wall + m * 4096 + (wn * 16 + lr) * 64 + ks * 32 + lg * 8);
  const float thv = temp[wn * 2 + (lg >> 1)];   // temp of head owning channels wn*16+lg*4

  // ---- phase A: issue halo loads (T1+T2) to regs, x tile to regs, dw weights ----
  int4 zero4; zero4.x = zero4.y = zero4.z = zero4.w = 0;
  int4 h1r[2], h2r[2], xtr;
#pragma unroll
  for (int i = 0; i < 2; ++i) {
    int cc = tid + i * 512;
    bool act = cc < 800;
    int prow = act ? (cc >> 3) : 0;
    int c8 = cc & 7;
    int hy = prow / 10, hx = prow - hy * 10;
    int gy = y0 - 1 + hy, gx = x0 - 1 + hx;
    bool ok = act && (unsigned)gy < 256u && (unsigned)gx < 256u;
    size_t ga = (((size_t)b * 256 + gy) * 256 + gx) * (size_t)64 + c8 * 8;
    h1r[i] = ok ? *(const int4*)(T1g + ga) : zero4;
    h2r[i] = ok ? *(const int4*)(T2g + ga) : zero4;
  }
  const size_t wbase = (((size_t)b * 256 + y0) * 256 + x0) * 64;
  xtr = *(const int4*)(xT + wbase + (size_t)(tid >> 6) * 16384 + (tid & 63) * 8);

  // write T1 halo, dw weights to LDS
#pragma unroll
  for (int i = 0; i < 2; ++i) {
    int cc = tid + i * 512;
    if (cc < 800) *(int4*)(sm + HALO + (cc >> 3) * 144 + (cc & 7) * 16) = h1r[i];
  }
  if (tid < 144) {
    int4 d = *(const int4*)(Wall + 16384 + tid * 8);
    *(int4*)(sm + DWW + tid * 16) = d;
  }
  __syncthreads();

  // ---- phase B/C/D: depthwise conv (packed f16) T1 -> INA; swap halo; T2 -> INB ----
  // per-pixel channel means computed inline (shfl reduce over the 8 c8-lanes)
  const half8 hz8 = {(h16)0, (h16)0, (h16)0, (h16)0, (h16)0, (h16)0, (h16)0, (h16)0};
#pragma unroll
  for (int pass = 0; pass < 2; ++pass) {
    const int outb = pass ? INB : INA;
    {
      const int px = tid >> 3, c8 = tid & 7;   // 512 tasks = 64 px x 8 ch-chunks
      const int py = px >> 3, pxx = px & 7;
      half8 af = hz8;
#pragma unroll
      for (int tap = 0; tap < 9; ++tap) {
        const int dy = tap / 3, dx = tap - dy * 3;
        half8 v  = *(const half8*)(sm + HALO + ((py + dy) * 10 + pxx + dx) * 144 + c8 * 16);
        half8 w8 = *(const half8*)(sm + DWW + pass * 1152 + tap * 128 + c8 * 16);
        af += v * w8;                           // v_pk_fma_f16 x4
      }
      *(half8*)(sm + outb + px * 144 + c8 * 16) = af;
      // fused channel mean: sum own 8 ch, reduce over c8 lanes (same wave)
      float s = 0.f;
#pragma unroll
      for (int j = 0; j < 8; ++j) s += (float)af[j];
      s += __shfl_xor(s, 1);
      s += __shfl_xor(s, 2);
      s += __shfl_xor(s, 4);
      if (c8 == 0) *(float*)(sm + SIN + pass * 256 + px * 4) = s * (1.f / 64.f);
    }
    __syncthreads();
    if (pass == 0) {
      // overwrite halo with T2
#pragma unroll
      for (int i = 0; i < 2; ++i) {
        int cc = tid + i * 512;
        if (cc < 800) *(int4*)(sm + HALO + (cc >> 3) * 144 + (cc & 7) * 16) = h2r[i];
      }
      __syncthreads();
    }
  }

  // ---- phase E: write x tile into INC ----
  {
    int py = tid >> 6, off = tid & 63;
    int px = py * 8 + (off >> 3);
    *(int4*)(sm + INC + px * 144 + (off & 7) * 16) = xtr;
  }
  __syncthreads();

  // ---- phase F: q,k,v GEMMs into registers (wave: co tile wn, px half wm) ----
  f32x4 aq[2], ak[2], av[2];
#pragma unroll
  for (int pi = 0; pi < 2; ++pi) {
    aq[pi] = (f32x4){0.f, 0.f, 0.f, 0.f};
    ak[pi] = (f32x4){0.f, 0.f, 0.f, 0.f};
    av[pi] = (f32x4){0.f, 0.f, 0.f, 0.f};
  }
  __builtin_amdgcn_s_setprio(1);
#pragma unroll
  for (int pi = 0; pi < 2; ++pi)
#pragma unroll
    for (int ks = 0; ks < 2; ++ks) {
      const int boff = (wm * 32 + pi * 16 + lr) * 144 + ks * 64 + lg * 16;
      half8 b0 = *(const half8*)(sm + INA + boff);
      half8 b1 = *(const half8*)(sm + INB + boff);
      half8 b2 = *(const half8*)(sm + INC + boff);
      aq[pi] = __builtin_amdgcn_mfma_f32_16x16x32_f16(wf[0][ks], b0, aq[pi], 0, 0, 0);
      ak[pi] = __builtin_amdgcn_mfma_f32_16x16x32_f16(wf[1][ks], b1, ak[pi], 0, 0, 0);
      av[pi] = __builtin_amdgcn_mfma_f32_16x16x32_f16(wf[2][ks], b2, av[pi], 0, 0, 0);
    }
  __builtin_amdgcn_s_setprio(0);
  __syncthreads();   // tile reads done; reuse LDS

  // ---- phase G: normalize/scale (log2e folded into q), write Q,K ([px][ch]) and VT ([ch][px]) ----
#pragma unroll
  for (int pi = 0; pi < 2; ++pi) {
    const int px = wm * 32 + pi * 16 + lr;
    const float si = *(const float*)(sm + SIN + px * 4);
    const float sn = *(const float*)(sm + SIN + 256 + px * 4);
    float s2 = aq[pi][0]*aq[pi][0] + aq[pi][1]*aq[pi][1] + aq[pi][2]*aq[pi][2] + aq[pi][3]*aq[pi][3];
    float qs = (1.f + si) * (0.35355339059327373f * 1.4426950408889634f) * thv /
               fmaxf(sqrtf(s2 + __shfl_xor(s2, 16)), 1e-12f);
    float k2 = ak[pi][0]*ak[pi][0] + ak[pi][1]*ak[pi][1] + ak[pi][2]*ak[pi][2] + ak[pi][3]*ak[pi][3];
    float ks2 = fminf(fmaxf(1.f - sn, 0.f), 1.f) /
                fmaxf(sqrtf(k2 + __shfl_xor(k2, 16)), 1e-12f);
    uint2 dq; dq.x = pk2(aq[pi][0]*qs, aq[pi][1]*qs); dq.y = pk2(aq[pi][2]*qs, aq[pi][3]*qs);
    uint2 dk; dk.x = pk2(ak[pi][0]*ks2, ak[pi][1]*ks2); dk.y = pk2(ak[pi][2]*ks2, ak[pi][3]*ks2);
    *(uint2*)(sm + INA + px * 144 + (wn * 16 + lg * 4) * 2) = dq;
    *(uint2*)(sm + INB + px * 144 + (wn * 16 + lg * 4) * 2) = dk;
#pragma unroll
    for (int r = 0; r < 4; ++r)
      *(h16*)(sm + INC + (wn * 16 + lg * 4 + r) * 144 + px * 2) = (h16)av[pi][r];
  }
  __syncthreads();

  // ---- phase H: attention via 32x32x16 MFMA; wave = head wv ----
  // scores pre-scaled by log2e -> p = exp2(s), no max-subtraction (|s| <= ~1.02*temp, bounded).
  // PV computed as O^T = mfma(V^T, P): D cols=q (all lanes), valid d in regs 0..3 (+4*hi) -> b64 AO store.
  const int l31 = lane & 31, hi = lane >> 5;
  const half8 hz = hz8;
  const f32x16 z16 = {0.f,0.f,0.f,0.f,0.f,0.f,0.f,0.f,0.f,0.f,0.f,0.f,0.f,0.f,0.f,0.f};
  {
    const int h = wv;
    half8 kfr[2], qfr[2];
#pragma unroll
    for (int kt = 0; kt < 2; ++kt)
      kfr[kt] = hi ? hz : *(const half8*)(sm + INB + (kt * 32 + l31) * 144 + h * 16);
#pragma unroll
    for (int qt = 0; qt < 2; ++qt)
      qfr[qt] = hi ? hz : *(const half8*)(sm + INA + (qt * 32 + l31) * 144 + h * 16);

#pragma unroll
    for (int qt = 0; qt < 2; ++qt) {
      __builtin_amdgcn_s_setprio(1);
      f32x16 s0 = __builtin_amdgcn_mfma_f32_32x32x16_f16(kfr[0], qfr[qt], z16, 0, 0, 0);
      f32x16 s1 = __builtin_amdgcn_mfma_f32_32x32x16_f16(kfr[1], qfr[qt], z16, 0, 0, 0);
      __builtin_amdgcn_s_setprio(0);
      float sum = 0.f;
#pragma unroll
      for (int i = 0; i < 16; ++i) { s0[i] = __builtin_amdgcn_exp2f(s0[i]); sum += s0[i]; }
#pragma unroll
      for (int i = 0; i < 16; ++i) { s1[i] = __builtin_amdgcn_exp2f(s1[i]); sum += s1[i]; }
      sum += __shfl_xor(sum, 32);
      const float inv = 1.f / sum;

      half8 pa[4];
#pragma unroll
      for (int st = 0; st < 4; ++st) {
        const int rb = (st & 1) * 8;
        float p0, p1, p2, p3, p4, p5, p6, p7;
        if (st < 2) {
          p0 = s0[rb+0]; p1 = s0[rb+1]; p2 = s0[rb+2]; p3 = s0[rb+3];
          p4 = s0[rb+4]; p5 = s0[rb+5]; p6 = s0[rb+6]; p7 = s0[rb+7];
        } else {
          p0 = s1[rb+0]; p1 = s1[rb+1]; p2 = s1[rb+2]; p3 = s1[rb+3];
          p4 = s1[rb+4]; p5 = s1[rb+5]; p6 = s1[rb+6]; p7 = s1[rb+7];
        }
        unsigned x0_ = pk2(p0, p1), x1_ = pk2(p2, p3);
        unsigned y0_ = pk2(p4, p5), y1_ = pk2(p6, p7);
        plswap(x0_, y0_);
        plswap(x1_, y1_);
        union { unsigned uu4[4]; half8 h; } uu;
        uu.uu4[0] = x0_; uu.uu4[1] = x1_; uu.uu4[2] = y0_; uu.uu4[3] = y1_;
        pa[st] = uu.h;
      }
      f32x16 oacc = z16;
      __builtin_amdgcn_s_setprio(1);
#pragma unroll
      for (int st = 0; st < 4; ++st) {
        half8 vfr = (l31 < 8)
          ? *(const half8*)(sm + INC + (h * 8 + l31) * 144 + (st * 16 + hi * 8) * 2)
          : hz;
        oacc = __builtin_amdgcn_mfma_f32_32x32x16_f16(vfr, pa[st], oacc, 0, 0, 0);
      }
      __builtin_amdgcn_s_setprio(0);
      // O^T: col=q=l31 (all lanes), rows d = r + 4*hi for r=0..3 -> one b64 store
      {
        uint2 dAO;
        dAO.x = pk2(oacc[0] * inv, oacc[1] * inv);
        dAO.y = pk2(oacc[2] * inv, oacc[3] * inv);
        *(uint2*)(sm + INA + (qt * 32 + l31) * 144 + (h * 8 + 4 * hi) * 2) = dAO;
      }
    }
  }
  __syncthreads();

  // ---- phase I: output projection (wave: co tile wn, px half wm) ----
  f32x4 pacc[2];
#pragma unroll
  for (int pi = 0; pi < 2; ++pi) pacc[pi] = (f32x4){0.f, 0.f, 0.f, 0.f};
  __builtin_amdgcn_s_setprio(1);
#pragma unroll
  for (int pi = 0; pi < 2; ++pi)
#pragma unroll
    for (int ks = 0; ks < 2; ++ks) {
      half8 bfr = *(const half8*)(sm + INA + (wm * 32 + pi * 16 + lr) * 144 + ks * 64 + lg * 16);
      pacc[pi] = __builtin_amdgcn_mfma_f32_16x16x32_f16(wf[3][ks], bfr, pacc[pi], 0, 0, 0);
    }
  __builtin_amdgcn_s_setprio(0);
#pragma unroll
  for (int pi = 0; pi < 2; ++pi) {
    const int px = wm * 32 + pi * 16 + lr;
    const int py = px >> 3, pxx = px & 7;
    const int co = wn * 16 + lg * 4;
    float* ob = out + ((size_t)(b * CC + co)) * HW + (size_t)(y0 + py) * W_ + (x0 + pxx);
    ob[0]      = pacc[pi][0];
    ob[HW]     = pacc[pi][1];
    ob[2 * HW] = pacc[pi][2];
    ob[3 * HW] = pacc[pi][3];
  }
}

extern "C" void kernel_launch(void* const* d_in, const int* in_sizes, int n_in,
                              void* d_out, int out_size, void* d_ws, size_t ws_size,
                              hipStream_t stream) {
  const float* x        = (const float*)d_in[0];
  const float* w_iem    = (const float*)d_in[1];
  const float* w_nem    = (const float*)d_in[2];
  const float* w_iem_dw = (const float*)d_in[3];
  const float* w_nem_dw = (const float*)d_in[4];
  const float* w_q      = (const float*)d_in[5];
  const float* w_k      = (const float*)d_in[6];
  const float* w_v      = (const float*)d_in[7];
  const float* w_proj   = (const float*)d_in[8];
  const float* temp     = (const float*)d_in[9];
  float* outp = (float*)d_out;

  const size_t PLE = (size_t)4 * CC * HW;   // 16,777,216 elems per f16 plane
  h16* h0   = (h16*)d_ws;
  h16* T1   = h0;                           // NHWC f16 sigmoid(conv(x,w_iem))
  h16* T2   = h0 + PLE;
  h16* xT   = h0 + 2 * PLE;
  h16* Bt   = h0 + 3 * PLE;
  h16* Wall = Bt + 73728;

  dim3 b256(256), b512(512);

  k_wprep    <<<dim3(288),        b256, 0, stream>>>(w_iem, w_nem, Bt);
  k_wprep2   <<<dim3(69),         b256, 0, stream>>>(w_q, w_k, w_v, w_proj,
                                                     w_iem_dw, w_nem_dw, Wall);
  k_xpose    <<<dim3(4, 256, 4),  b256, 0, stream>>>(x, xT);
  k_conv3x3x2<<<dim3(4, 128, 4),  b512, 0, stream>>>(xT, Bt, T1, T2);
  k_megaattn <<<dim3(4096),       b512, 0, stream>>>(T1, T2, xT, Wall, temp, outp);
}